// Round 2
// baseline (244.484 us; speedup 1.0000x reference)
//
#include <hip/hip_runtime.h>

#define N_TOK 256
#define CP    128
#define CHD   32
#define NH    4
#define NT    65536   // N_TOK*N_TOK
#define NCOL  528     // 512 (q|k|v|g) + 4 (b) + 12 pad
#define PNS   136     // padded LDS stride (shorts)

typedef short short8 __attribute__((ext_vector_type(8)));
typedef float f32x4  __attribute__((ext_vector_type(4)));
typedef float float4v __attribute__((ext_vector_type(4)));
typedef unsigned uint2v __attribute__((ext_vector_type(2)));

__device__ __forceinline__ short f2bf(float f) {
    unsigned u = __builtin_bit_cast(unsigned, f);
    u += 0x7fffu + ((u >> 16) & 1u);   // RTNE
    return (short)(u >> 16);
}
__device__ __forceinline__ float bf2f(short s) {
    unsigned u = ((unsigned)(unsigned short)s) << 16;
    return __builtin_bit_cast(float, u);
}

// ---------------------------------------------------------------- kernel 0
__global__ void pack_weights(const float* __restrict__ Wq, const float* __restrict__ Wk,
                             const float* __restrict__ Wv, const float* __restrict__ Wb,
                             const float* __restrict__ Wg, const float* __restrict__ Wout,
                             short* __restrict__ wcat, short* __restrict__ woutT) {
    int idx = blockIdx.x * 256 + threadIdx.x;
    if (idx < NCOL * CP) {
        int n = idx >> 7, k = idx & 127;
        float v = 0.f;
        if (n < 512) {
            const float* W = (n < 128) ? Wq : (n < 256) ? Wk : (n < 384) ? Wv : Wg;
            v = W[k * 128 + (n & 127)];
        } else if (n < 516) {
            v = Wb[k * 4 + (n - 512)];
        }
        wcat[n * CP + k] = f2bf(v);
    } else {
        int j = idx - NCOL * CP;
        if (j < 128 * 128) {
            int n = j >> 7, k = j & 127;
            woutT[n * 128 + k] = f2bf(Wout[k * 128 + n]);
        }
    }
}

// ---------------------------------------------------------------- kernel 1
// LayerNorm (fp32, width-32 shuffles) + projections (bf16 MFMA, 8-chunk
// groups with all accumulators live -> ILP on B-fragment loads).
// Zero barriers: each wave owns its 16 rows end-to-end.
__global__ __launch_bounds__(256, 4)
void ln_proj(const float* __restrict__ pair, const float* __restrict__ gamma,
             const float* __restrict__ beta, const short* __restrict__ wcat,
             short* __restrict__ qt, short* __restrict__ kt,
             short* __restrict__ vt, short* __restrict__ gt,
             float* __restrict__ bt) {
    __shared__ short pn[64 * PNS];     // normalized bf16 x
    __shared__ short sbuf[64 * PNS];   // C-tile staging for coalesced stores
    const int tid = threadIdx.x;
    const int wv = tid >> 6, lane = tid & 63;
    const int quad = lane >> 4, l15 = lane & 15;
    const int r0 = blockIdx.x * 64;
    const int c = lane & 31, half = lane >> 5;

    float4v ga = *(const float4v*)&gamma[4 * c];
    float4v be = *(const float4v*)&beta[4 * c];

    // phase 1: LN.  2 rows/pass (32 lanes per row), dwordx4 loads.
    #pragma unroll 4
    for (int p = 0; p < 8; ++p) {
        int row = wv * 16 + p * 2 + half;
        float4v x = *(const float4v*)(pair + (size_t)(r0 + row) * CP + 4 * c);
        float s  = (x[0] + x[1]) + (x[2] + x[3]);
        float q2 = (x[0] * x[0] + x[1] * x[1]) + (x[2] * x[2] + x[3] * x[3]);
        #pragma unroll
        for (int m = 1; m < 32; m <<= 1) {
            s  += __shfl_xor(s, m, 32);
            q2 += __shfl_xor(q2, m, 32);
        }
        float mu = s * (1.f / 128.f);
        float var = q2 * (1.f / 128.f) - mu * mu;
        float rs = rsqrtf(var + 1e-5f);
        unsigned y0 = (unsigned)(unsigned short)f2bf((x[0] - mu) * rs * ga[0] + be[0]);
        unsigned y1 = (unsigned)(unsigned short)f2bf((x[1] - mu) * rs * ga[1] + be[1]);
        unsigned y2 = (unsigned)(unsigned short)f2bf((x[2] - mu) * rs * ga[2] + be[2]);
        unsigned y3 = (unsigned)(unsigned short)f2bf((x[3] - mu) * rs * ga[3] + be[3]);
        uint2v pk = {y0 | (y1 << 16), y2 | (y3 << 16)};
        *(uint2v*)&pn[row * PNS + 4 * c] = pk;   // wave-private rows; in-order LDS
    }

    short8 afrag[4];
    #pragma unroll
    for (int s = 0; s < 4; ++s)
        afrag[s] = *(const short8*)&pn[(wv * 16 + l15) * PNS + s * 32 + quad * 8];

    // phase 2: 4 groups of 8 chunks (q, k, v, g), then bias chunk.
    for (int grp = 0; grp < 4; ++grp) {
        f32x4 acc[8];
        #pragma unroll
        for (int c8 = 0; c8 < 8; ++c8) {
            acc[c8] = f32x4{0.f, 0.f, 0.f, 0.f};
            #pragma unroll
            for (int s = 0; s < 4; ++s) {
                short8 bfrag = *(const short8*)&wcat[(size_t)(grp * 128 + c8 * 16 + l15) * CP + s * 32 + quad * 8];
                acc[c8] = __builtin_amdgcn_mfma_f32_16x16x32_bf16(afrag[s], bfrag, acc[c8], 0, 0, 0);
            }
        }
        if (grp == 3) {
            #pragma unroll
            for (int c8 = 0; c8 < 8; ++c8)
                #pragma unroll
                for (int r = 0; r < 4; ++r)
                    acc[c8][r] = 1.f / (1.f + __expf(-acc[c8][r]));   // sigmoid gate
        }
        // C-layout -> LDS (wave-private rows, no barrier)
        #pragma unroll
        for (int c8 = 0; c8 < 8; ++c8)
            #pragma unroll
            for (int r = 0; r < 4; ++r)
                sbuf[(wv * 16 + quad * 4 + r) * PNS + c8 * 16 + l15] = f2bf(acc[c8][r]);
        // coalesced read-back + dwordx4 global stores (full 64B lines)
        int row = wv * 16 + (lane >> 2);
        short* dst = (grp == 0) ? qt : (grp == 1) ? kt : (grp == 2) ? vt : gt;
        #pragma unroll
        for (int rep = 0; rep < 4; ++rep) {   // rep = head
            short8 v8 = *(const short8*)&sbuf[row * PNS + rep * 32 + (lane & 3) * 8];
            *(short8*)(dst + ((size_t)rep * NT + r0 + row) * CHD + (lane & 3) * 8) = v8;
        }
    }
    // bias chunk (n = 512..527; rows 516+ are zero-padded)
    f32x4 accb = f32x4{0.f, 0.f, 0.f, 0.f};
    #pragma unroll
    for (int s = 0; s < 4; ++s) {
        short8 bfrag = *(const short8*)&wcat[(size_t)(512 + l15) * CP + s * 32 + quad * 8];
        accb = __builtin_amdgcn_mfma_f32_16x16x32_bf16(afrag[s], bfrag, accb, 0, 0, 0);
    }
    if (l15 < 4) {
        #pragma unroll
        for (int r = 0; r < 4; ++r)
            bt[l15 * NT + r0 + wv * 16 + quad * 4 + r] = accb[r];
    }
}

// ---------------------------------------------------------------- kernel 2
// Attention per (i,h).  One barrier total (after v staging); pl is
// wave-private.  XOR-swizzled LDS (stride 256, phys = colblk ^ (row&7))
// -> conflict-free ds_read_b128 in the PV loop.
__global__ __launch_bounds__(256)
void attn(const short* __restrict__ qt, const short* __restrict__ kt,
          const short* __restrict__ vt, const short* __restrict__ gt,
          const float* __restrict__ bt, short* __restrict__ og) {
    __shared__ short vT[32 * 256];    // [c][key], swizzled
    __shared__ short pl[64 * 256];    // [j_local][key], swizzled, wave-private
    const int tid = threadIdx.x;
    const int h = blockIdx.x >> 8, i = blockIdx.x & 255;
    const int wv = tid >> 6, lane = tid & 63;
    const int quad = lane >> 4, l15 = lane & 15;

    const short* kbase = kt + ((size_t)h * NT + (size_t)i * 256) * CHD;
    const short* vbase = vt + ((size_t)h * NT + (size_t)i * 256) * CHD;
    const short* qbase = qt + ((size_t)h * NT + (size_t)i * 256) * CHD;
    const short* gbase = gt + ((size_t)h * NT + (size_t)i * 256) * CHD;
    const float* bbase = bt + (size_t)h * NT;

    for (int g = tid; g < 1024; g += 256) {
        int key = g >> 2, p = g & 3;
        short8 s8 = *(const short8*)(vbase + key * CHD + p * 8);
        #pragma unroll
        for (int cc = 0; cc < 8; ++cc) {
            int row = p * 8 + cc;
            int phys = (key >> 3) ^ (row & 7);
            vT[row * 256 + phys * 8 + (key & 7)] = s8[cc];
        }
    }
    __syncthreads();

    const float scale = 0.17677669529663687f;  // 1/sqrt(32)

    for (int jt = 0; jt < 4; ++jt) {
        int jbase = jt * 64 + wv * 16;
        short8 aq = *(const short8*)(qbase + (jbase + l15) * CHD + quad * 8);

        f32x4 sacc[16];
        #pragma unroll
        for (int t = 0; t < 16; ++t) {
            short8 bk = *(const short8*)(kbase + (t * 16 + l15) * CHD + quad * 8);
            f32x4 z = {0.f, 0.f, 0.f, 0.f};
            sacc[t] = __builtin_amdgcn_mfma_f32_16x16x32_bf16(aq, bk, z, 0, 0, 0);
        }
        #pragma unroll
        for (int t = 0; t < 16; ++t)
            #pragma unroll
            for (int r = 0; r < 4; ++r) {
                int j = jbase + quad * 4 + r;
                sacc[t][r] = sacc[t][r] * scale + bbase[(size_t)j * 256 + t * 16 + l15];
            }
        float mx[4] = {-1e30f, -1e30f, -1e30f, -1e30f}, sm[4] = {0.f, 0.f, 0.f, 0.f};
        #pragma unroll
        for (int t = 0; t < 16; ++t)
            #pragma unroll
            for (int r = 0; r < 4; ++r) mx[r] = fmaxf(mx[r], sacc[t][r]);
        #pragma unroll
        for (int m = 1; m < 16; m <<= 1)
            #pragma unroll
            for (int r = 0; r < 4; ++r) mx[r] = fmaxf(mx[r], __shfl_xor(mx[r], m, 16));
        #pragma unroll
        for (int t = 0; t < 16; ++t)
            #pragma unroll
            for (int r = 0; r < 4; ++r) {
                float e = __expf(sacc[t][r] - mx[r]);
                sacc[t][r] = e;
                sm[r] += e;
            }
        #pragma unroll
        for (int m = 1; m < 16; m <<= 1)
            #pragma unroll
            for (int r = 0; r < 4; ++r) sm[r] += __shfl_xor(sm[r], m, 16);
        float inv[4];
        #pragma unroll
        for (int r = 0; r < 4; ++r) inv[r] = 1.f / sm[r];
        // P -> LDS (C-layout write, swizzled; wave-private, no barrier)
        #pragma unroll
        for (int t = 0; t < 16; ++t)
            #pragma unroll
            for (int r = 0; r < 4; ++r) {
                int prow = wv * 16 + quad * 4 + r;
                int phys = (2 * t + (l15 >> 3)) ^ (prow & 7);
                pl[prow * 256 + phys * 8 + (l15 & 7)] = f2bf(sacc[t][r] * inv[r]);
            }
        // PV
        f32x4 oacc[2];
        oacc[0] = f32x4{0.f, 0.f, 0.f, 0.f};
        oacc[1] = f32x4{0.f, 0.f, 0.f, 0.f};
        #pragma unroll
        for (int ks = 0; ks < 8; ++ks) {
            int physp = ((ks * 4 + quad) ^ (l15 & 7)) * 8;
            short8 ap = *(const short8*)&pl[(wv * 16 + l15) * 256 + physp];
            #pragma unroll
            for (int nt = 0; nt < 2; ++nt) {
                short8 bv = *(const short8*)&vT[(nt * 16 + l15) * 256 + physp];
                oacc[nt] = __builtin_amdgcn_mfma_f32_16x16x32_bf16(ap, bv, oacc[nt], 0, 0, 0);
            }
        }
        // gate + store
        #pragma unroll
        for (int nt = 0; nt < 2; ++nt) {
            int cc = nt * 16 + l15;
            #pragma unroll
            for (int r = 0; r < 4; ++r) {
                int j = jbase + quad * 4 + r;
                float gv = bf2f(gbase[(size_t)j * CHD + cc]);
                og[((size_t)i * 256 + j) * CP + h * CHD + cc] = f2bf(oacc[nt][r] * gv);
            }
        }
    }
}

// ---------------------------------------------------------------- kernel 3
__global__ __launch_bounds__(256, 4)
void out_gemm(const short* __restrict__ og, const short* __restrict__ woutT,
              float* __restrict__ out) {
    __shared__ short al[64 * PNS];
    const int tid = threadIdx.x;
    const int wv = tid >> 6, lane = tid & 63;
    const int quad = lane >> 4, l15 = lane & 15;
    const int r0 = blockIdx.x * 64;

    for (int g = tid; g < 1024; g += 256) {
        int row = g >> 4, p = g & 15;
        *(short8*)&al[row * PNS + p * 8] = *(const short8*)(og + (size_t)(r0 + row) * CP + p * 8);
    }
    __syncthreads();

    short8 af[4];
    #pragma unroll
    for (int s = 0; s < 4; ++s)
        af[s] = *(const short8*)&al[(wv * 16 + l15) * PNS + s * 32 + quad * 8];

    f32x4 acc[8];
    #pragma unroll
    for (int ch = 0; ch < 8; ++ch) {
        acc[ch] = f32x4{0.f, 0.f, 0.f, 0.f};
        #pragma unroll
        for (int s = 0; s < 4; ++s) {
            short8 bfrag = *(const short8*)&woutT[(size_t)(ch * 16 + l15) * 128 + s * 32 + quad * 8];
            acc[ch] = __builtin_amdgcn_mfma_f32_16x16x32_bf16(af[s], bfrag, acc[ch], 0, 0, 0);
        }
    }
    #pragma unroll
    for (int ch = 0; ch < 8; ++ch)
        #pragma unroll
        for (int r = 0; r < 4; ++r)
            out[(size_t)(r0 + wv * 16 + quad * 4 + r) * CP + ch * 16 + l15] = acc[ch][r];
}

// ---------------------------------------------------------------- launch
extern "C" void kernel_launch(void* const* d_in, const int* in_sizes, int n_in,
                              void* d_out, int out_size, void* d_ws, size_t ws_size,
                              hipStream_t stream) {
    (void)in_sizes; (void)n_in; (void)out_size; (void)ws_size;
    const float* pair  = (const float*)d_in[0];
    const float* gamma = (const float*)d_in[1];
    const float* beta  = (const float*)d_in[2];
    const float* Wq    = (const float*)d_in[3];
    const float* Wk    = (const float*)d_in[4];
    const float* Wv    = (const float*)d_in[5];
    const float* Wb    = (const float*)d_in[6];
    const float* Wg    = (const float*)d_in[7];
    const float* Wout  = (const float*)d_in[8];
    float* out = (float*)d_out;

    char* ws = (char*)d_ws;
    const size_t SZ_QKVG = (size_t)NH * NT * CHD * 2;           // 16 MB each
    short* wcat  = (short*)(ws);
    short* woutT = (short*)(ws + 135168);
    short* qt    = (short*)(ws + 167936);
    short* kt    = (short*)(ws + 167936 + SZ_QKVG);
    short* vt    = (short*)(ws + 167936 + 2 * SZ_QKVG);
    short* gt    = (short*)(ws + 167936 + 3 * SZ_QKVG);
    float* bt    = (float*)(ws + 167936 + 4 * SZ_QKVG);
    short* og    = (short*)(ws + 167936 + 4 * SZ_QKVG + (size_t)NH * NT * 4);

    hipLaunchKernelGGL(pack_weights, dim3(328), dim3(256), 0, stream,
                       Wq, Wk, Wv, Wb, Wg, Wout, wcat, woutT);
    hipLaunchKernelGGL(ln_proj, dim3(1024), dim3(256), 0, stream,
                       pair, gamma, beta, wcat, qt, kt, vt, gt, bt);
    hipLaunchKernelGGL(attn, dim3(1024), dim3(256), 0, stream,
                       qt, kt, vt, gt, bt, og);
    hipLaunchKernelGGL(out_gemm, dim3(1024), dim3(256), 0, stream,
                       og, woutT, out);
}